// Round 4
// baseline (4797.173 us; speedup 1.0000x reference)
//
#include <hip/hip_runtime.h>
#include <hip/hip_bf16.h>

typedef unsigned int u32;
typedef unsigned short u16;
typedef unsigned long long u64;
typedef __attribute__((ext_vector_type(8))) short short8;
typedef __attribute__((ext_vector_type(4))) float floatx4;

#define L_SEQ 256
#define BATCH 64
#define DIM 1024
#define GROUPS 8      // independent batch groups (8 rows each)
#define GWGS 32       // WGs per group, each owns 32 d-cols
#define GROWS 8       // batch rows per group

__device__ __forceinline__ float b2f(u16 u) {
  union { u32 i; float f; } v; v.i = ((u32)u) << 16; return v.f;
}
__device__ __forceinline__ u16 f2b(float f) {
  union { float f; u32 i; } v; v.f = f;
  u32 r = v.i + 0x7FFFu + ((v.i >> 16) & 1u);
  return (u16)(r >> 16);
}

__device__ __forceinline__ void st_u32_llc(u32* p, u32 v) {
  asm volatile("global_store_dword %0, %1, off sc0 sc1"
               :: "v"((u64)(uintptr_t)p), "v"(v) : "memory");
}
__device__ __forceinline__ u32 ld_u32_llc(const u32* p) {
  u32 v;
  asm volatile("global_load_dword %0, %1, off sc0 sc1\n\ts_waitcnt vmcnt(0)"
               : "=v"(v) : "v"((u64)(uintptr_t)p) : "memory");
  return v;
}

// -------- c-write + release -------------------------------------------------
// c exchanged as PACKED u32 words (2 bf16/word; K-dim permuted per 32-col
// block so a lane's two values are adjacent).
// LOCAL=true : returning atomic swaps (sc0 = return-old) — vmcnt clears only
//   when the TCC returns the old value, i.e. the new value is provably IN
//   the XCD L2 (and DIRTY there — key for the read path). Then a
//   non-returning TCC atomic bumps the counter.
// LOCAL=false: sc0 sc1 dword stores ack at the LLC; agent-scope bump.
template<bool LOCAL>
__device__ __forceinline__ void c_write_publish(
    u32* gcnt, u16* cwr, int act, int cb_off,
    u32 pk0, u32 pk1, u32 pk2, u32 pk3)
{
  if (act) {
    const u64 a0 = (u64)(uintptr_t)cwr + (u32)cb_off;
    const u64 a1 = a0 + 2048, a2 = a0 + 4096, a3 = a0 + 6144;
    if constexpr (LOCAL) {
      u32 o0, o1, o2, o3;
      asm volatile(
        "global_atomic_swap %0, %4, %8, off sc0\n\t"
        "global_atomic_swap %1, %5, %9, off sc0\n\t"
        "global_atomic_swap %2, %6, %10, off sc0\n\t"
        "global_atomic_swap %3, %7, %11, off sc0\n\t"
        "s_waitcnt vmcnt(0)"
        : "=&v"(o0), "=&v"(o1), "=&v"(o2), "=&v"(o3)
        : "v"(a0), "v"(a1), "v"(a2), "v"(a3),
          "v"(pk0), "v"(pk1), "v"(pk2), "v"(pk3)
        : "memory");
    } else {
      asm volatile(
        "global_store_dword %0, %4, off sc0 sc1\n\t"
        "global_store_dword %1, %5, off sc0 sc1\n\t"
        "global_store_dword %2, %6, off sc0 sc1\n\t"
        "global_store_dword %3, %7, off sc0 sc1\n\t"
        "s_waitcnt vmcnt(0)"
        :: "v"(a0), "v"(a1), "v"(a2), "v"(a3),
           "v"(pk0), "v"(pk1), "v"(pk2), "v"(pk3)
        : "memory");
    }
  }
  __builtin_amdgcn_sched_barrier(0);
  if (threadIdx.x == 0) {
    if constexpr (LOCAL)
      asm volatile("global_atomic_add %0, %1, off"
                   :: "v"((u64)(uintptr_t)gcnt), "v"(1u) : "memory");
    else
      __hip_atomic_fetch_add(gcnt, 1u, __ATOMIC_RELAXED, __HIP_MEMORY_SCOPE_AGENT);
  }
}

// -------- group wait --------------------------------------------------------
// ROUNDS 1-3 BUG (diagnosed via pytest1_s 8s -> 85s = 1028 waits x 2^20-iter
// cap x ~190cy = ~80s): the LOCAL poll used an sc0-only PLAIN LOAD, which is
// served CU-side (stale) and never sees the TCC counter -> every wait capped.
// FIX: poll with a RETURNING atomic add of 0 (sc0 = return-old). It executes
// in the TCC, so it architecturally cannot read a stale CU-side copy.
template<bool LOCAL>
__device__ __forceinline__ void g_wait_t(u32* c, u32 tgt) {
  if (threadIdx.x == 0) {
    if constexpr (LOCAL) {
      u32 v, it = 0;
      const u64 a = (u64)(uintptr_t)c;
      const u32 z = 0;
      do {
        asm volatile("global_atomic_add %0, %1, %2, off sc0\n\ts_waitcnt vmcnt(0)"
                     : "=v"(v) : "v"(a), "v"(z) : "memory");
      } while (v < tgt && ++it < (1u << 20));   // cap: fail loud, never hang
    } else {
      while (__hip_atomic_load(c, __ATOMIC_RELAXED, __HIP_MEMORY_SCOPE_AGENT) < tgt)
        __builtin_amdgcn_s_sleep(1);
    }
  }
  __syncthreads();
}

// full-WG arrive for the one-time handshake only
__device__ __forceinline__ void g_arrive_full(u32* c) {
  __syncthreads();
  if (threadIdx.x == 0)
    __hip_atomic_fetch_add(c, 1u, __ATOMIC_RELAXED, __HIP_MEMORY_SCOPE_AGENT);
}

__global__ void zero_cnt(u32* p) {
  #pragma unroll
  for (int i = 0; i < 8; ++i) p[threadIdx.x * 8 + i] = 0;   // 8 KB
}

// -------- weight convert+transpose: W[k][n] fp32 -> WT[n][k] bf16, 6 mats ---
__global__ __launch_bounds__(256) void transpose6(
    const float* __restrict__ w0, const float* __restrict__ w1,
    const float* __restrict__ w2, const float* __restrict__ w3,
    const float* __restrict__ w4, const float* __restrict__ w5,
    u16* __restrict__ wt)
{
  __shared__ u16 tile[64][66];
  const int z = blockIdx.z;
  const float* src = z==0?w0: z==1?w1: z==2?w2: z==3?w3: z==4?w4: w5;
  u16* dst = wt + (size_t)z * DIM * DIM;
  const int k0 = blockIdx.x * 64, n0 = blockIdx.y * 64;
  const int r = threadIdx.x & 63, q = threadIdx.x >> 6;
  #pragma unroll 4
  for (int rep = 0; rep < 16; ++rep) {
    int k = q * 16 + rep;
    tile[k][r] = f2b(src[(size_t)(k0 + k) * DIM + n0 + r]);
  }
  __syncthreads();
  #pragma unroll 4
  for (int rep = 0; rep < 16; ++rep) {
    int n = q * 16 + rep;
    dst[(size_t)(n0 + n) * DIM + k0 + r] = tile[r][n];
  }
}

// -------- embedding gather: fp32 emb -> bf16 X ------------------------------
__global__ __launch_bounds__(256) void embed_gather(
    const int* __restrict__ xs, const float* __restrict__ emb, u16* __restrict__ Xb)
{
  const int t = blockIdx.x * 256 + threadIdx.x;
  const int row = t >> 8, ch = t & 255;
  const int tok = xs[row];
  float4 v = *(const float4*)(emb + (size_t)tok * DIM + ch * 4);
  union { ushort4 s; u16 u[4]; } o;
  o.u[0] = f2b(v.x); o.u[1] = f2b(v.y); o.u[2] = f2b(v.z); o.u[3] = f2b(v.w);
  *(ushort4*)(Xb + (size_t)row * DIM + ch * 4) = o.s;
}

// -------- input projections: Y = X @ W + b, bf16 MFMA, fp32 accum -----------
__global__ __launch_bounds__(256) void proj3(
    const u16* __restrict__ X, const u16* __restrict__ WTbase,
    const float* __restrict__ bi, const float* __restrict__ bfp,
    const float* __restrict__ bc,
    u16* __restrict__ XI, u16* __restrict__ XF, u16* __restrict__ XC)
{
  __shared__ __align__(16) u16 ldsA[8 * 64 * 8];
  __shared__ __align__(16) u16 ldsB[8 * 64 * 8];
  const int z = blockIdx.z;
  const u16* WT = WTbase + (size_t)z * DIM * DIM;
  const float* bias = z == 0 ? bi : (z == 1 ? bfp : bc);
  u16* Y = z == 0 ? XI : (z == 1 ? XF : XC);
  const int m0 = blockIdx.x * 128, n0 = blockIdx.y * 128;
  const int tid = threadIdx.x;
  const int l = tid & 63, w = tid >> 6;
  const int wm = w >> 1, wn = w & 1;

  floatx4 acc[4][4];
  #pragma unroll
  for (int i = 0; i < 4; ++i)
    #pragma unroll
    for (int j = 0; j < 4; ++j) acc[i][j] = (floatx4){0, 0, 0, 0};

  const int srow = tid >> 2, sch = tid & 3;
  for (int k0 = 0; k0 < DIM; k0 += 32) {
    #pragma unroll
    for (int rr = 0; rr < 2; ++rr) {
      int row = rr * 64 + srow;
      uint4 va = *(const uint4*)(X  + (size_t)(m0 + row) * DIM + k0 + sch * 8);
      uint4 vb = *(const uint4*)(WT + (size_t)(n0 + row) * DIM + k0 + sch * 8);
      int slot = ((row >> 4) * 64 + (row & 15) + 16 * sch) * 8;
      *(uint4*)(ldsA + slot) = va;
      *(uint4*)(ldsB + slot) = vb;
    }
    __syncthreads();
    short8 af[4], bf8[4];
    #pragma unroll
    for (int i = 0; i < 4; ++i) af[i]  = *(const short8*)(ldsA + ((wm * 4 + i) * 64 + l) * 8);
    #pragma unroll
    for (int j = 0; j < 4; ++j) bf8[j] = *(const short8*)(ldsB + ((wn * 4 + j) * 64 + l) * 8);
    #pragma unroll
    for (int i = 0; i < 4; ++i)
      #pragma unroll
      for (int j = 0; j < 4; ++j)
        acc[i][j] = __builtin_amdgcn_mfma_f32_16x16x32_bf16(af[i], bf8[j], acc[i][j], 0, 0, 0);
    __syncthreads();
  }
  const int lq = l >> 4, lc = l & 15;
  #pragma unroll
  for (int j = 0; j < 4; ++j) {
    int col = n0 + wn * 64 + j * 16 + lc;
    float bv = bias[col];
    #pragma unroll
    for (int i = 0; i < 4; ++i)
      #pragma unroll
      for (int r = 0; r < 4; ++r) {
        int row = m0 + wm * 64 + i * 16 + lq * 4 + r;
        Y[(size_t)row * DIM + col] = f2b(acc[i][j][r] + bv);
      }
  }
}

// -------- recurrent scan body (templated on communication scope) ------------
template<bool LOCAL>
__device__ __forceinline__ void scan_body(
    const u16* __restrict__ XI, const u16* __restrict__ XF,
    const u16* __restrict__ XC, u16* __restrict__ Xb,
    float* __restrict__ HoutF, u16* __restrict__ cgrp,
    float* __restrict__ cf32, u32* gcnt,
    const short8 (&bregs)[8][2][2], floatx4 (*part)[2][2][64],
    int reverse, int load_c, int write_out, int g8, int d0)
{
  const int tid = threadIdx.x, l = tid & 63, w = tid >> 6;
  const int q = l >> 4, lr = l & 15;
  const int act = (w == 0) && (q < 2);    // lanes doing elementwise (rows q*4..q*4+3)
  const int mrow = q * 4;
  // byte offset of this lane's packed u32 (permuted pos p=2*lr) for row mrow
  const int cb_off = mrow * 2048 + 2 * d0 + 4 * lr;

  float creg[2][4];
  float xi[2][4], xf[2][4], xc[2][4], xv[2][4];
  int t = reverse ? (L_SEQ - 1) : 0;
  const int dt = reverse ? -1 : 1;

  if (act) {
    #pragma unroll
    for (int nt = 0; nt < 2; ++nt)
      #pragma unroll
      for (int r = 0; r < 4; ++r) {
        const int b = g8 + mrow + r, d = d0 + nt * 16 + lr;
        creg[nt][r] = load_c ? cf32[(size_t)b * DIM + d] : 0.0f;
      }
  }
  {
    u32 pk0 = 0, pk1 = 0, pk2 = 0, pk3 = 0;
    if (act) {
      pk0 = (u32)f2b(creg[0][0]) | ((u32)f2b(creg[1][0]) << 16);
      pk1 = (u32)f2b(creg[0][1]) | ((u32)f2b(creg[1][1]) << 16);
      pk2 = (u32)f2b(creg[0][2]) | ((u32)f2b(creg[1][2]) << 16);
      pk3 = (u32)f2b(creg[0][3]) | ((u32)f2b(creg[1][3]) << 16);
    }
    c_write_publish<LOCAL>(gcnt, cgrp, act, cb_off, pk0, pk1, pk2, pk3);  // buffer 0
  }
  if (act) {
    // prefetch step-0 gates (overlaps the wait)
    const size_t base = (size_t)t * (BATCH * DIM);
    #pragma unroll
    for (int nt = 0; nt < 2; ++nt)
      #pragma unroll
      for (int r = 0; r < 4; ++r) {
        const size_t idx = base + (size_t)(g8 + mrow + r) * DIM + d0 + nt * 16 + lr;
        xi[nt][r] = b2f(__builtin_nontemporal_load(XI + idx));
        xf[nt][r] = b2f(__builtin_nontemporal_load(XF + idx));
        xc[nt][r] = b2f(__builtin_nontemporal_load(XC + idx));
        xv[nt][r] = b2f(__builtin_nontemporal_load(Xb + idx));
      }
  }

  u32 epoch = 1;
  g_wait_t<LOCAL>(gcnt, GWGS * epoch); ++epoch;

  for (int step = 0; step < L_SEQ; ++step, t += dt) {
    const size_t base = (size_t)t * (BATCH * DIM);
    const u16* crd = cgrp + (size_t)(step & 1) * (GROWS * DIM);
    u16* cwr = cgrp + (size_t)((step + 1) & 1) * (GROWS * DIM);

    // A fragments: row = lr (valid 0..7), k = w*256 + kk8*32 + q*8 + j
    // (PERMUTED k-space; bregs match, so dot products unchanged).
    // sc0 sc1 reads: bypass all CU-side caching under either SC-bit model;
    // the c lines are DIRTY in the local TCC (atomic-swap written), so the
    // local L2 services them on the request path. Trailing vmcnt(0)
    // completes before the part-barrier -> WAR safety for the bump.
    uint4 afr[8];
    if (lr < 8) {
      const u64 ab = (u64)(uintptr_t)crd + (u32)(lr * 2048 + w * 512 + q * 16);
      asm volatile(
        "global_load_dwordx4 %0, %8, off sc0 sc1\n\t"
        "global_load_dwordx4 %1, %8, off offset:64 sc0 sc1\n\t"
        "global_load_dwordx4 %2, %8, off offset:128 sc0 sc1\n\t"
        "global_load_dwordx4 %3, %8, off offset:192 sc0 sc1\n\t"
        "global_load_dwordx4 %4, %8, off offset:256 sc0 sc1\n\t"
        "global_load_dwordx4 %5, %8, off offset:320 sc0 sc1\n\t"
        "global_load_dwordx4 %6, %8, off offset:384 sc0 sc1\n\t"
        "global_load_dwordx4 %7, %8, off offset:448 sc0 sc1\n\t"
        "s_waitcnt vmcnt(0)"
        : "=&v"(afr[0]), "=&v"(afr[1]), "=&v"(afr[2]), "=&v"(afr[3]),
          "=&v"(afr[4]), "=&v"(afr[5]), "=&v"(afr[6]), "=&v"(afr[7])
        : "v"(ab)
        : "memory");
    } else {
      #pragma unroll
      for (int i = 0; i < 8; ++i) afr[i] = (uint4){0, 0, 0, 0};
    }

    floatx4 acc[2][2];
    #pragma unroll
    for (int nt = 0; nt < 2; ++nt)
      #pragma unroll
      for (int g = 0; g < 2; ++g) acc[nt][g] = (floatx4){0, 0, 0, 0};
    #pragma unroll
    for (int kk8 = 0; kk8 < 8; ++kk8) {
      const short8 a = __builtin_bit_cast(short8, afr[kk8]);
      #pragma unroll
      for (int nt = 0; nt < 2; ++nt) {
        acc[nt][0] = __builtin_amdgcn_mfma_f32_16x16x32_bf16(a, bregs[kk8][nt][0], acc[nt][0], 0, 0, 0);
        acc[nt][1] = __builtin_amdgcn_mfma_f32_16x16x32_bf16(a, bregs[kk8][nt][1], acc[nt][1], 0, 0, 0);
      }
    }
    #pragma unroll
    for (int nt = 0; nt < 2; ++nt) {
      part[w][nt][0][l] = acc[nt][0];
      part[w][nt][1][l] = acc[nt][1];
    }
    __syncthreads();

    // --- critical path: gates -> c' -> atomic-swap write -> release ---
    if (act) {
      floatx4 sI[2], sF[2];
      #pragma unroll
      for (int nt = 0; nt < 2; ++nt) {
        sI[nt] = part[0][nt][0][l]; sF[nt] = part[0][nt][1][l];
        #pragma unroll
        for (int pw = 1; pw < 4; ++pw) { sI[nt] += part[pw][nt][0][l]; sF[nt] += part[pw][nt][1][l]; }
      }
      #pragma unroll
      for (int nt = 0; nt < 2; ++nt)
        #pragma unroll
        for (int r = 0; r < 4; ++r) {
          const float iv = 1.0f / (1.0f + __expf(-(xi[nt][r] + sI[nt][r])));
          const float fv = 1.0f / (1.0f + __expf(-(xf[nt][r] + sF[nt][r])));
          creg[nt][r] = iv * xc[nt][r] + fv * creg[nt][r];
        }
    }
    {
      u32 pk0 = 0, pk1 = 0, pk2 = 0, pk3 = 0;
      if (act) {
        pk0 = (u32)f2b(creg[0][0]) | ((u32)f2b(creg[1][0]) << 16);
        pk1 = (u32)f2b(creg[0][1]) | ((u32)f2b(creg[1][1]) << 16);
        pk2 = (u32)f2b(creg[0][2]) | ((u32)f2b(creg[1][2]) << 16);
        pk3 = (u32)f2b(creg[0][3]) | ((u32)f2b(creg[1][3]) << 16);
      }
      c_write_publish<LOCAL>(gcnt, cwr, act, cb_off, pk0, pk1, pk2, pk3);
    }

    // --- off the critical path: h, output stores, next-step prefetch ---
    if (act) {
      #pragma unroll
      for (int nt = 0; nt < 2; ++nt)
        #pragma unroll
        for (int r = 0; r < 4; ++r) {
          const float hv = tanhf(creg[nt][r]) + xv[nt][r];
          const int d = d0 + nt * 16 + lr;
          const size_t idx = base + (size_t)(g8 + mrow + r) * DIM + d;
          __builtin_nontemporal_store(f2b(hv), Xb + idx);
          if (write_out) __builtin_nontemporal_store(hv, HoutF + idx);
        }
      if (step + 1 < L_SEQ) {
        const size_t nb = (size_t)(t + dt) * (BATCH * DIM);
        #pragma unroll
        for (int nt = 0; nt < 2; ++nt)
          #pragma unroll
          for (int r = 0; r < 4; ++r) {
            const size_t idx = nb + (size_t)(g8 + mrow + r) * DIM + d0 + nt * 16 + lr;
            xi[nt][r] = b2f(__builtin_nontemporal_load(XI + idx));
            xf[nt][r] = b2f(__builtin_nontemporal_load(XF + idx));
            xc[nt][r] = b2f(__builtin_nontemporal_load(XC + idx));
            xv[nt][r] = b2f(__builtin_nontemporal_load(Xb + idx));
          }
      }
    }
    g_wait_t<LOCAL>(gcnt, GWGS * epoch); ++epoch;
  }

  if (act) {
    #pragma unroll
    for (int nt = 0; nt < 2; ++nt)
      #pragma unroll
      for (int r = 0; r < 4; ++r)
        cf32[(size_t)(g8 + mrow + r) * DIM + d0 + nt * 16 + lr] = creg[nt][r];
  }
}

// -------- recurrent scan: 8 independent groups x 32 WGs ---------------------
// group owns batch rows [g*8, g*8+8); WG owns d-cols [member*32, member*32+32)
// Runtime check: if all 32 members of the group share one XCD (round-robin
// blockIdx%8 dispatch), exchange c through the XCD-local L2 (returning atomic
// swaps = provable commit; returning-atomic poll = provable freshness).
// Else fall back to LLC path.
__global__ __launch_bounds__(256, 1) void ran_scan_g(
    const float* __restrict__ Wic, const float* __restrict__ Wfc,
    const u16* __restrict__ XI, const u16* __restrict__ XF,
    const u16* __restrict__ XC,
    u16* __restrict__ Xb,        // bf16 x: residual in, h out (in-place, NT)
    float* __restrict__ HoutF,   // fp32 h out (only when write_out)
    u16* __restrict__ cbf,       // per-group dbuf bf16 c: [8][2][8][1024] (K-permuted)
    float* __restrict__ cf32,    // fp32 c carried between scans (natural layout)
    u32* __restrict__ cnt,       // LLC counters, per-scan region (group line at +g*32)
    u32* __restrict__ fcnt,      // L2 fast counters, per-scan region (group line at +g*16)
    u32* __restrict__ xcdtab,    // 8 groups x 32 members: observed XCC_ID
    int reverse, int load_c, int write_out)
{
  __shared__ floatx4 part[4][2][2][64];   // [k-wave][n-tile][gate][lane]
  const int tid = threadIdx.x, l = tid & 63, w = tid >> 6;
  const int group = blockIdx.x & 7, member = blockIdx.x >> 3;
  const int q = l >> 4, lr = l & 15;
  const int d0 = member * 32;
  const int g8 = group * GROWS;
  u16* cgrp = cbf + (size_t)group * (2 * GROWS * DIM);

  // B fragments in VGPRs: [kk8][n-tile][mat]; wave w covers k in [w*256,(w+1)*256).
  // K-dim PERMUTED within each 32-col block to match packed c layout:
  // permuted pos p (= k&31) holds original col ((p&1)<<4) | (p>>1).
  short8 bregs[8][2][2];
  for (int kk8 = 0; kk8 < 8; ++kk8) {
    const int kbase = w * 256 + kk8 * 32 + q * 8;
    #pragma unroll
    for (int nt = 0; nt < 2; ++nt) {
      const int n = d0 + nt * 16 + lr;
      #pragma unroll
      for (int g = 0; g < 2; ++g) {
        const float* W = g ? Wfc : Wic;
        union { short8 v; u16 u[8]; } tmp;
        #pragma unroll
        for (int j = 0; j < 8; ++j) {
          const int k = kbase + j;
          const int p = k & 31;
          const int orig = (k & ~31) | ((p & 1) << 4) | (p >> 1);
          tmp.u[j] = f2b(W[(size_t)orig * DIM + n]);
        }
        bregs[kk8][nt][g] = tmp.v;
      }
    }
  }

  // ---- XCD locality handshake (always through LLC, one-time) ----
  u32 xcc;
  asm volatile("s_getreg_b32 %0, hwreg(HW_REG_XCC_ID)" : "=s"(xcc));
  u32* gchk = cnt + group * 32 + 8;          // separate word from loop counter
  if (tid == 0) st_u32_llc(xcdtab + group * 32 + member, xcc);
  g_arrive_full(gchk);
  g_wait_t<false>(gchk, GWGS);
  u32 o = xcc;
  if (l < 32) o = ld_u32_llc(xcdtab + group * 32 + l);
  const int lok = __all(o == xcc);           // identical across all members

  if (lok)
    scan_body<true>(XI, XF, XC, Xb, HoutF, cgrp, cf32, fcnt + group * 16,
                    bregs, part, reverse, load_c, write_out, g8, d0);
  else
    scan_body<false>(XI, XF, XC, Xb, HoutF, cgrp, cf32, cnt + group * 32,
                     bregs, part, reverse, load_c, write_out, g8, d0);
}

// -------- launcher ----------------------------------------------------------
extern "C" void kernel_launch(void* const* d_in, const int* in_sizes, int n_in,
                              void* d_out, int out_size, void* d_ws, size_t ws_size,
                              hipStream_t stream) {
  (void)in_sizes; (void)out_size; (void)ws_size;
  const int* xs = (const int*)d_in[0];
  const float* emb = (const float*)d_in[1];
  const float* W[18];
  for (int i = 0; i < 18 && i < n_in; ++i) W[i] = (const float*)d_in[i];

  char* ws = (char*)d_ws;
  u32* cnt    = (u32*)ws;                            // 8 KB: slow cnt (0..4K),
                                                     // fast cnt (4..6K), xcdtab (6..7K)
  u16* WT     = (u16*)(ws + 8192);                   // 6 x [1024][1024] bf16
  u16* Xb     = (u16*)(ws + 12591104ull);            // [256][64][1024] bf16, in place
  u16* XIb    = (u16*)(ws + 46145536ull);
  u16* XFb    = (u16*)(ws + 79699968ull);
  u16* XCb    = (u16*)(ws + 113254400ull);
  u16* cbf    = (u16*)(ws + 146808832ull);           // [8][2][8][1024] bf16 = 256 KB
  float* cf32 = (float*)(ws + 147070976ull);         // [64][1024] fp32

  zero_cnt<<<1, 256, 0, stream>>>(cnt);
  transpose6<<<dim3(16, 16, 6), 256, 0, stream>>>(W[2], W[4], W[6], W[10], W[12], W[14], WT);
  embed_gather<<<16384, 256, 0, stream>>>(xs, emb, Xb);

  for (int s = 0; s < 4; ++s) {
    const int p = s & 1;   // 0 = forward(fw weights), 1 = reverse(bw weights)
    const u16* WTs = WT + (size_t)p * 3 * DIM * DIM;
    proj3<<<dim3(128, 8, 3), 256, 0, stream>>>(
        Xb, WTs, W[p ? 15 : 7], W[p ? 16 : 8], W[p ? 17 : 9], XIb, XFb, XCb);
    ran_scan_g<<<256, 256, 0, stream>>>(
        W[p ? 11 : 3], W[p ? 13 : 5], XIb, XFb, XCb, Xb, (float*)d_out,
        cbf, cf32, cnt + s * 256, cnt + 1024 + s * 128, cnt + 1536,
        p, s > 0 ? 1 : 0, s == 3 ? 1 : 0);
  }
}